// Round 16
// baseline (416.872 us; speedup 1.0000x reference)
//
#include <hip/hip_runtime.h>
#include <math.h>

#define BATCH 4
#define NPTS 4096
#define DF 64
#define ROWB 128               // bytes per point row in bf16
#define RB 128                 // rows per block
#define CB 1024                // cols per block (chunk)
#define TILE 128               // cols per staged tile
#define ITERS (CB / TILE)      // 8
#define NT (NPTS / RB)         // 32 row tiles
#define NCS (NPTS / CB)        // 4 col chunks
#define INV_T 100.0f
#define MARGIN 0.16f           // skipped weights < e^-16 vs exact local min
#define SCALE (1.0f / 16384.0f)

typedef float  f32x4 __attribute__((ext_vector_type(4)));
typedef short  s16x8 __attribute__((ext_vector_type(8)));
typedef unsigned short u16;
typedef unsigned int u32;

// ws layout (11.4 MB)
#define SZ_B   (BATCH * NPTS * DF * 2)   // bf16 array: 2 MB
#define SZ_N   (BATCH * NPTS * 4)        // norm array: 64 KB
#define SZ_PROW (BATCH * NCS * NPTS * 3 * 4)   // 786 KB
#define SZ_PCOL (BATCH * NT * NPTS * 3 * 4)    // 6.3 MB
#define OFF_XB 0
#define OFF_YB (OFF_XB + SZ_B)
#define OFF_X2 (OFF_YB + SZ_B)
#define OFF_Y2 (OFF_X2 + SZ_N)
#define OFF_PROW (OFF_Y2 + SZ_N)
#define OFF_PCOL (OFF_PROW + SZ_PROW)

__device__ __forceinline__ u16 f2bf(float f) {
    unsigned u = __float_as_uint(f);
    unsigned r = (u + 0x7fffu + ((u >> 16) & 1u)) >> 16;   // RNE
    return (u16)r;
}

// async 16B global -> LDS (DMA)
__device__ __forceinline__ void async16(void* lds, const void* g) {
    __builtin_amdgcn_global_load_lds(
        (const __attribute__((address_space(1))) unsigned int*)g,
        (__attribute__((address_space(3))) unsigned int*)lds, 16, 0, 0);
}

// monotone float<->uint key (for atomicMax over signed floats)
__device__ __forceinline__ u32 fkey(float f) {
    u32 u = __float_as_uint(f);
    return (u & 0x80000000u) ? ~u : (u | 0x80000000u);
}
__device__ __forceinline__ float fdekey(u32 k) {
    u32 u = (k & 0x80000000u) ? (k ^ 0x80000000u) : ~k;
    return __uint_as_float(u);
}

// fp32 -> bf16 (XOR-swizzled row layout: byte ^= (point&7)<<4) + fp32 norms.
__global__ __launch_bounds__(256) void prep_kernel(const float* __restrict__ X,
                                                   const float* __restrict__ Y,
                                                   u16* __restrict__ xb, u16* __restrict__ yb,
                                                   float* __restrict__ x2, float* __restrict__ y2,
                                                   float* __restrict__ out) {
    if (blockIdx.x == 0 && blockIdx.y == 0 && threadIdx.x == 0) out[0] = 0.0f;
    const float* src = blockIdx.y ? Y : X;
    u16* dstb   = blockIdx.y ? yb : xb;
    float* dstn = blockIdx.y ? y2 : x2;
    int g = blockIdx.x * 256 + threadIdx.x;
    int p = g >> 4;
    int sub = g & 15;
    float4 v = ((const float4*)src)[(size_t)p * 16 + sub];
    float n4 = v.x * v.x + v.y * v.y + v.z * v.z + v.w * v.w;
    #pragma unroll
    for (int m = 1; m < 16; m <<= 1) n4 += __shfl_xor(n4, m, 16);
    ushort4 hh;
    hh.x = f2bf(v.x); hh.y = f2bf(v.y); hh.z = f2bf(v.z); hh.w = f2bf(v.w);
    int byteoff = (sub << 3) ^ ((p & 7) << 4);
    *(ushort4*)((char*)dstb + (size_t)p * ROWB + byteoff) = hh;
    if (sub == 0) dstn[p] = n4;
}

// SHARED-U two-phase softmin: one block computes the 128x1024 U'-tile
// (u' = -d^2/2 via MFMA C seeded with -(x^2+y^2)/2) ONCE, serving BOTH
// directions: row-wise (registers) and col-wise (LDS atomics) min+sums.
__global__ __launch_bounds__(512) void softmin_shared(const u16* __restrict__ xb,
                                                      const u16* __restrict__ yb,
                                                      const float* __restrict__ x2g,
                                                      const float* __restrict__ y2g,
                                                      float* __restrict__ prow,
                                                      float* __restrict__ pcol) {
    __shared__ u16 ys[2][TILE * DF];     // 32 KB double buffer
    __shared__ float cyS[CB];            // 4 KB col norms
    __shared__ u32 colG[CB];             // 4 KB: pass1 max-key -> pass2 gthr_col
    __shared__ float colSS[CB], colTT[CB]; // 8 KB col sums
    __shared__ float xchg[8][32][2];     // 2 KB cross-wcol row merge

    const int tid = threadIdx.x;
    const int nt = blockIdx.x;
    const int b  = blockIdx.y & 3;
    const int cs = blockIdx.y >> 2;

    const int w = tid >> 6, wrow = w >> 1, wcol = w & 1;
    const int h = (tid >> 4) & 3, c = tid & 15;

    const size_t bpts = (size_t)b * NPTS;
    const char* rbase = (const char*)(xb + (bpts + (size_t)nt * RB) * DF);
    const char* cbase = (const char*)(yb + (bpts + (size_t)cs * CB) * DF);
    const float* cnb = y2g + bpts + (size_t)cs * CB;
    const float* rnb = x2g + bpts + (size_t)nt * RB;

    // loop-invariant B offsets + col ids (4 x 16-col groups per 128-col tile)
    int boff[4][2], pty[4];
    #pragma unroll
    for (int ct = 0; ct < 4; ++ct) {
        int p = wcol * 64 + ct * 16 + c;
        pty[ct] = p;
        #pragma unroll
        for (int kp = 0; kp < 2; ++kp)
            boff[ct][kp] = p * ROWB + ((h * 16 + kp * 64) ^ ((p & 7) << 4));
    }

    // ---- prologue ----
    for (int j = tid; j < CB; j += 512) colG[j] = 0u;   // below fkey(-inf)
    #pragma unroll
    for (int q = 0; q < 2; ++q) {
        int e = q * 512 + tid;
        async16((char*)ys[0] + e * 16, cbase + e * 16);
    }
    if (tid < 256) *(float4*)&cyS[tid * 4] = ((const float4*)cnb)[tid];

    s16x8 afrag[2][2];
    #pragma unroll
    for (int st = 0; st < 2; ++st) {
        int rr = wrow * 32 + st * 16 + c;
        #pragma unroll
        for (int kp = 0; kp < 2; ++kp) {
            int o = (h * 16 + kp * 64) ^ ((rr & 7) << 4);
            afrag[st][kp] = *(const s16x8*)(rbase + rr * ROWB + o);
        }
    }
    float nx2[2][4];                     // -x^2/2 for this lane's 8 rows
    #pragma unroll
    for (int st = 0; st < 2; ++st)
        #pragma unroll
        for (int r = 0; r < 4; ++r)
            nx2[st][r] = -0.5f * rnb[wrow * 32 + st * 16 + 4 * h + r];

    float mx[2][4];
    #pragma unroll
    for (int st = 0; st < 2; ++st)
        #pragma unroll
        for (int r = 0; r < 4; ++r) mx[st][r] = -INFINITY;

    __syncthreads();   // drains DMA + LDS init

    // ================= PASS 1: max of u' = -d^2/2, rows AND cols ============
    for (int it = 0; it < ITERS; ++it) {
        if (it > 0) __syncthreads();
        if (it + 1 < ITERS) {
            const char* nsrc = cbase + (size_t)(it + 1) * TILE * ROWB;
            char* nbuf = (char*)ys[(it + 1) & 1];
            #pragma unroll
            for (int q = 0; q < 2; ++q) {
                int e = q * 512 + tid;
                async16(nbuf + e * 16, nsrc + e * 16);
            }
        }
        const char* bptr = (const char*)ys[it & 1];

        #pragma unroll
        for (int ct = 0; ct < 4; ++ct) {
            s16x8 b0 = *(const s16x8*)(bptr + boff[ct][0]);
            s16x8 b1 = *(const s16x8*)(bptr + boff[ct][1]);
            float ny = -0.5f * cyS[it * TILE + pty[ct]];
            float cm = -INFINITY;
            #pragma unroll
            for (int st = 0; st < 2; ++st) {
                f32x4 seed = {nx2[st][0] + ny, nx2[st][1] + ny,
                              nx2[st][2] + ny, nx2[st][3] + ny};
                f32x4 a = __builtin_amdgcn_mfma_f32_16x16x32_bf16(afrag[st][0], b0, seed, 0, 0, 0);
                a = __builtin_amdgcn_mfma_f32_16x16x32_bf16(afrag[st][1], b1, a, 0, 0, 0);
                #pragma unroll
                for (int r = 0; r < 4; ++r) {
                    mx[st][r] = fmaxf(mx[st][r], a[r]);
                    cm = fmaxf(cm, a[r]);
                }
            }
            // col-max: reduce over the 4 h-groups (32 rows), then LDS atomic
            cm = fmaxf(cm, __shfl_xor(cm, 16));
            cm = fmaxf(cm, __shfl_xor(cm, 32));
            if (h == 0) atomicMax(&colG[it * TILE + pty[ct]], fkey(cm));
        }
    }

    // ---- pass1 epilogue ----
    #pragma unroll
    for (int st = 0; st < 2; ++st)
        #pragma unroll
        for (int r = 0; r < 4; ++r)
            #pragma unroll
            for (int m = 1; m < 16; m <<= 1)
                mx[st][r] = fmaxf(mx[st][r], __shfl_xor(mx[st][r], m, 16));
    __syncthreads();                     // colG final; xchg safe
    if (c == 0) {
        #pragma unroll
        for (int st = 0; st < 2; ++st)
            #pragma unroll
            for (int r = 0; r < 4; ++r)
                xchg[w][st * 16 + 4 * h + r][0] = mx[st][r];
    }
    // col interlude: key -> gthr_col (u' domain); zero col sums
    for (int j = tid; j < CB; j += 512) {
        float um = fdekey(colG[j]);
        float dc = sqrtf(fmaxf(-2.f * um, 0.f));
        float dt = dc + MARGIN;
        colG[j] = __float_as_uint(-0.5f * dt * dt);
        colSS[j] = 0.f; colTT[j] = 0.f;
    }
    __syncthreads();
    #pragma unroll
    for (int st = 0; st < 2; ++st)
        #pragma unroll
        for (int r = 0; r < 4; ++r)
            mx[st][r] = fmaxf(mx[st][r], xchg[w ^ 1][st * 16 + 4 * h + r][0]);

    float gthr[2][4], ssum[2][4], tsum[2][4];
    #pragma unroll
    for (int st = 0; st < 2; ++st)
        #pragma unroll
        for (int r = 0; r < 4; ++r) {
            float dmin = sqrtf(fmaxf(-2.f * mx[st][r], 0.f));   // exact row min
            float dt = dmin + MARGIN;
            gthr[st][r] = -0.5f * dt * dt;       // a > gthr <=> d < dmin+MARGIN
            ssum[st][r] = 0.f; tsum[st][r] = 0.f;
        }

    // re-stage tile 0
    #pragma unroll
    for (int q = 0; q < 2; ++q) {
        int e = q * 512 + tid;
        async16((char*)ys[0] + e * 16, cbase + e * 16);
    }

    // ================= PASS 2: gated weighted sums, both directions =========
    for (int it = 0; it < ITERS; ++it) {
        __syncthreads();
        if (it + 1 < ITERS) {
            const char* nsrc = cbase + (size_t)(it + 1) * TILE * ROWB;
            char* nbuf = (char*)ys[(it + 1) & 1];
            #pragma unroll
            for (int q = 0; q < 2; ++q) {
                int e = q * 512 + tid;
                async16(nbuf + e * 16, nsrc + e * 16);
            }
        }
        const char* bptr = (const char*)ys[it & 1];

        #pragma unroll
        for (int ct = 0; ct < 4; ++ct) {
            s16x8 b0 = *(const s16x8*)(bptr + boff[ct][0]);
            s16x8 b1 = *(const s16x8*)(bptr + boff[ct][1]);
            int j = it * TILE + pty[ct];
            float ny = -0.5f * cyS[j];
            float gc = __uint_as_float(colG[j]);
            #pragma unroll
            for (int st = 0; st < 2; ++st) {
                f32x4 seed = {nx2[st][0] + ny, nx2[st][1] + ny,
                              nx2[st][2] + ny, nx2[st][3] + ny};
                f32x4 a = __builtin_amdgcn_mfma_f32_16x16x32_bf16(afrag[st][0], b0, seed, 0, 0, 0);
                a = __builtin_amdgcn_mfma_f32_16x16x32_bf16(afrag[st][1], b1, a, 0, 0, 0);
                #pragma unroll
                for (int r = 0; r < 4; ++r) {
                    int hit = (a[r] > gthr[st][r]) | (a[r] > gc);
                    if (__any(hit)) {    // rare: slice near row-min or col-min
                        float d = sqrtf(fmaxf(-2.f * a[r], 0.f));
                        float dtr = sqrtf(-2.f * gthr[st][r]);
                        float er = __expf(INV_T * (dtr - d));   // ->0 if far
                        ssum[st][r] += er;
                        tsum[st][r] = fmaf(er, d, tsum[st][r]);
                        float dtc = sqrtf(-2.f * gc);
                        float ec = __expf(INV_T * (dtc - d));   // ->0 if far
                        atomicAdd(&colSS[j], ec);
                        atomicAdd(&colTT[j], ec * d);
                    }
                }
            }
        }
    }

    // ---- epilogue: rows ----
    #pragma unroll
    for (int st = 0; st < 2; ++st)
        #pragma unroll
        for (int r = 0; r < 4; ++r)
            #pragma unroll
            for (int m = 1; m < 16; m <<= 1) {
                ssum[st][r] += __shfl_xor(ssum[st][r], m, 16);
                tsum[st][r] += __shfl_xor(tsum[st][r], m, 16);
            }
    __syncthreads();                     // col atomics done; xchg reuse safe
    if (c == 0) {
        #pragma unroll
        for (int st = 0; st < 2; ++st)
            #pragma unroll
            for (int r = 0; r < 4; ++r) {
                int row32 = st * 16 + 4 * h + r;
                xchg[w][row32][0] = ssum[st][r];
                xchg[w][row32][1] = tsum[st][r];
            }
    }
    __syncthreads();
    if (wcol == 0 && c == 0) {
        #pragma unroll
        for (int st = 0; st < 2; ++st)
            #pragma unroll
            for (int r = 0; r < 4; ++r) {
                int row32 = st * 16 + 4 * h + r;
                float S = ssum[st][r] + xchg[w + 1][row32][0];
                float T = tsum[st][r] + xchg[w + 1][row32][1];
                float dtr = sqrtf(-2.f * gthr[st][r]);
                int row = nt * RB + wrow * 32 + row32;
                float* pp = prow + ((size_t)(b * NCS + cs) * NPTS + row) * 3;
                pp[0] = dtr; pp[1] = S; pp[2] = T;
            }
    }
    // ---- epilogue: cols ----
    for (int j = tid; j < CB; j += 512) {
        float gc = __uint_as_float(colG[j]);
        float dtc = sqrtf(-2.f * gc);
        int col = cs * CB + j;
        float* pp = pcol + ((size_t)(b * NT + nt) * NPTS + col) * 3;
        pp[0] = dtc; pp[1] = colSS[j]; pp[2] = colTT[j];
    }
}

// rows: merge NCS=4 partials, cube, reduce
__global__ __launch_bounds__(256) void merge_rows(const float* __restrict__ prow,
                                                  float* __restrict__ out) {
    __shared__ float red[4];
    int g = blockIdx.x * 256 + threadIdx.x;   // b*4096 + row
    int b = g >> 12, row = g & 4095;
    float mnv[NCS], sv[NCS], tv[NCS];
    float nm = INFINITY;
    #pragma unroll
    for (int k = 0; k < NCS; ++k) {
        const float* p = prow + ((size_t)(b * NCS + k) * NPTS + row) * 3;
        mnv[k] = p[0]; sv[k] = p[1]; tv[k] = p[2];
        nm = fminf(nm, mnv[k]);
    }
    float S = 0.f, T = 0.f;
    #pragma unroll
    for (int k = 0; k < NCS; ++k) {
        float cw = __expf(INV_T * (nm - mnv[k]));
        S += sv[k] * cw;
        T += tv[k] * cw;
    }
    float sm = T / S;
    float v = sm * sm * sm * SCALE;
    #pragma unroll
    for (int m = 1; m < 64; m <<= 1) v += __shfl_xor(v, m, 64);
    if ((threadIdx.x & 63) == 0) red[threadIdx.x >> 6] = v;
    __syncthreads();
    if (threadIdx.x == 0) atomicAdd(out, red[0] + red[1] + red[2] + red[3]);
}

// cols: online-merge NT=32 partials, cube, reduce
__global__ __launch_bounds__(256) void merge_cols(const float* __restrict__ pcol,
                                                  float* __restrict__ out) {
    __shared__ float red[4];
    int g = blockIdx.x * 256 + threadIdx.x;   // b*4096 + col
    int b = g >> 12, col = g & 4095;
    float ref = INFINITY, S = 0.f, T = 0.f;
    #pragma unroll 4
    for (int k = 0; k < NT; ++k) {
        const float* p = pcol + ((size_t)(b * NT + k) * NPTS + col) * 3;
        float rk = p[0], sk = p[1], tk = p[2];
        float nm = fminf(ref, rk);
        float e0 = __expf(INV_T * (nm - ref));   // exp(-inf)=0 on first
        float e1 = __expf(INV_T * (nm - rk));
        S = S * e0 + sk * e1;
        T = T * e0 + tk * e1;
        ref = nm;
    }
    float sm = T / S;
    float v = sm * sm * sm * SCALE;
    #pragma unroll
    for (int m = 1; m < 64; m <<= 1) v += __shfl_xor(v, m, 64);
    if ((threadIdx.x & 63) == 0) red[threadIdx.x >> 6] = v;
    __syncthreads();
    if (threadIdx.x == 0) atomicAdd(out, red[0] + red[1] + red[2] + red[3]);
}

extern "C" void kernel_launch(void* const* d_in, const int* in_sizes, int n_in,
                              void* d_out, int out_size, void* d_ws, size_t ws_size,
                              hipStream_t stream) {
    const float* x = (const float*)d_in[0];
    const float* y = (const float*)d_in[1];
    float* out = (float*)d_out;
    char* ws = (char*)d_ws;

    u16* xb = (u16*)(ws + OFF_XB);
    u16* yb = (u16*)(ws + OFF_YB);
    float* x2 = (float*)(ws + OFF_X2);
    float* y2 = (float*)(ws + OFF_Y2);
    float* prow = (float*)(ws + OFF_PROW);
    float* pcol = (float*)(ws + OFF_PCOL);

    prep_kernel<<<dim3(1024, 2), 256, 0, stream>>>(x, y, xb, yb, x2, y2, out);
    softmin_shared<<<dim3(NT, 16), 512, 0, stream>>>(xb, yb, x2, y2, prow, pcol);
    merge_rows<<<64, 256, 0, stream>>>(prow, out);
    merge_cols<<<64, 256, 0, stream>>>(pcol, out);
}

// Round 17
// 86.179 us; speedup vs baseline: 4.8373x; 4.8373x over previous
//
#include <hip/hip_runtime.h>
#include <math.h>

#define BATCH 4
#define NPTS 4096
#define DF 64
#define ROWB 128               // bytes per point row in bf16
#define TILE 128               // col tile per iter
#define MC 4                   // col chunks
#define CHUNK (NPTS / MC)      // 1024
#define ITERS (CHUNK / TILE)   // 8
#define INV_T 100.0f
#define MARGIN 0.16f           // skipped weights < exp(-16) ~ 1.1e-7
#define HM2C (0.5f * MARGIN * MARGIN)
#define SCALE (1.0f / 16384.0f)

typedef float  f32x4 __attribute__((ext_vector_type(4)));
typedef short  s16x8 __attribute__((ext_vector_type(8)));
typedef unsigned short u16;

// ws layout (6.19 MB, proven)
#define SZ_B   (BATCH * NPTS * DF * 2)   // bf16 array: 2 MB
#define SZ_N   (BATCH * NPTS * 4)        // norm array: 64 KB
#define OFF_XB 0
#define OFF_YB (OFF_XB + SZ_B)
#define OFF_X2 (OFF_YB + SZ_B)
#define OFF_Y2 (OFF_X2 + SZ_N)
#define OFF_PART (OFF_Y2 + SZ_N)         // [dirb][MC][NPTS][4] floats: 2 MB

__device__ __forceinline__ u16 f2bf(float f) {
    unsigned u = __float_as_uint(f);
    unsigned r = (u + 0x7fffu + ((u >> 16) & 1u)) >> 16;   // RNE
    return (u16)r;
}

// async 16B global -> LDS (DMA, no VGPR round-trip)
__device__ __forceinline__ void async16(void* lds, const void* g) {
    __builtin_amdgcn_global_load_lds(
        (const __attribute__((address_space(1))) unsigned int*)g,
        (__attribute__((address_space(3))) unsigned int*)lds, 16, 0, 0);
}

// fp32 -> bf16 (XOR-swizzled row layout: byte ^= (point&7)<<4) + fp32 norms.
__global__ __launch_bounds__(256) void prep_kernel(const float* __restrict__ X,
                                                   const float* __restrict__ Y,
                                                   u16* __restrict__ xb, u16* __restrict__ yb,
                                                   float* __restrict__ x2, float* __restrict__ y2,
                                                   float* __restrict__ out) {
    if (blockIdx.x == 0 && blockIdx.y == 0 && threadIdx.x == 0) out[0] = 0.0f;
    const float* src = blockIdx.y ? Y : X;
    u16* dstb   = blockIdx.y ? yb : xb;
    float* dstn = blockIdx.y ? y2 : x2;
    int g = blockIdx.x * 256 + threadIdx.x;
    int p = g >> 4;                       // point 0..16383
    int sub = g & 15;                     // 8B chunk within row
    float4 v = ((const float4*)src)[(size_t)p * 16 + sub];
    float n4 = v.x * v.x + v.y * v.y + v.z * v.z + v.w * v.w;
    #pragma unroll
    for (int m = 1; m < 16; m <<= 1) n4 += __shfl_xor(n4, m, 16);
    ushort4 hh;
    hh.x = f2bf(v.x); hh.y = f2bf(v.y); hh.z = f2bf(v.z); hh.w = f2bf(v.w);
    int byteoff = (sub << 3) ^ ((p & 7) << 4);   // swizzle (XOR bits 4..6)
    *(ushort4*)((char*)dstb + (size_t)p * ROWB + byteoff) = hh;
    if (sub == 0) dstn[p] = n4;
}

// Two-phase partial softmin (R14 skeleton + micro-cuts). Block = 64 rows x
// 1024 cols, wave tiling 2x2. MFMA C seeded with -y2/2 so u = a[r]. Pass 1:
// ct-paired max (v_max3-friendly). Pass 2: per-(st,ct) combined gate, dthr
// precomputed in registers.
__global__ __launch_bounds__(256, 4) void softmin_fused(const u16* __restrict__ xb,
                                                        const u16* __restrict__ yb,
                                                        const float* __restrict__ x2g,
                                                        const float* __restrict__ y2g,
                                                        float* __restrict__ part) {
    __shared__ u16 ys[2][TILE * DF];     // 2 x 16 KB double buffer
    __shared__ float cyS[CHUNK];         // 4 KB col norms
    __shared__ float xchg[4][32][2];

    const int tid = threadIdx.x;
    const int nt  = blockIdx.x;
    const int b   = blockIdx.y & 3;
    const int cs  = blockIdx.y >> 2;
    const int dir = blockIdx.z;

    const u16 *rowsrc, *colsrc; const float *rn, *cn;
    if (dir == 0) { rowsrc = xb; colsrc = yb; rn = x2g; cn = y2g; }
    else          { rowsrc = yb; colsrc = xb; rn = y2g; cn = x2g; }

    const int w    = tid >> 6;
    const int wrow = w >> 1, wcol = w & 1;
    const int h    = (tid >> 4) & 3;     // k-octet / D-row group
    const int c    = tid & 15;           // fragment lane slot

    const size_t bpts = (size_t)b * NPTS;
    const int row0 = nt * 64;
    const char* rbase = (const char*)(rowsrc + (bpts + row0) * DF);
    const char* cbase = (const char*)(colsrc + (bpts + (size_t)cs * CHUNK) * DF);
    const float* cnb = cn + bpts + (size_t)cs * CHUNK;

    // loop-invariant B fragment offsets + col point ids (4 x 16-col groups)
    int boff[4][2], pty[4];
    #pragma unroll
    for (int ct = 0; ct < 4; ++ct) {
        int p = wcol * 64 + ct * 16 + c;
        pty[ct] = p;
        #pragma unroll
        for (int kp = 0; kp < 2; ++kp)
            boff[ct][kp] = p * ROWB + ((h * 16 + kp * 64) ^ ((p & 7) << 4));
    }

    // ---- prologue: DMA first y tile; stage col norms; A-frags from global ----
    #pragma unroll
    for (int q = 0; q < 4; ++q) {
        int e = q * 256 + tid;
        async16((char*)ys[0] + e * 16, cbase + e * 16);
    }
    *(float4*)&cyS[tid * 4] = ((const float4*)cnb)[tid];   // 1024 col norms

    s16x8 afrag[2][2];
    #pragma unroll
    for (int st = 0; st < 2; ++st) {
        int rr = (wrow * 2 + st) * 16 + c;
        #pragma unroll
        for (int kp = 0; kp < 2; ++kp) {
            int o = (h * 16 + kp * 64) ^ ((rr & 7) << 4);
            afrag[st][kp] = *(const s16x8*)(rbase + rr * ROWB + o);
        }
    }
    float x2v[2][4];
    #pragma unroll
    for (int st = 0; st < 2; ++st)
        #pragma unroll
        for (int r = 0; r < 4; ++r)
            x2v[st][r] = rn[bpts + row0 + (wrow * 2 + st) * 16 + 4 * h + r];

    float mx[2][4];
    #pragma unroll
    for (int st = 0; st < 2; ++st)
        #pragma unroll
        for (int r = 0; r < 4; ++r) mx[st][r] = -INFINITY;

    __syncthreads();   // drains DMA + cyS writes

    // ================= PASS 1: chunk max of u = x.y - y2/2 (ct-paired) ======
    for (int it = 0; it < ITERS; ++it) {
        if (it > 0) __syncthreads();     // tile(it) DMA drained
        if (it + 1 < ITERS) {            // issue next tile (overlaps compute)
            const char* nsrc = cbase + (size_t)(it + 1) * TILE * ROWB;
            char* nbuf = (char*)ys[(it + 1) & 1];
            #pragma unroll
            for (int q = 0; q < 4; ++q) {
                int e = q * 256 + tid;
                async16(nbuf + e * 16, nsrc + e * 16);
            }
        }
        const char* bptr = (const char*)ys[it & 1];

        #pragma unroll
        for (int cp = 0; cp < 2; ++cp) {      // ct pair (2cp, 2cp+1)
            const int ct0 = cp * 2, ct1 = cp * 2 + 1;
            s16x8 b00 = *(const s16x8*)(bptr + boff[ct0][0]);
            s16x8 b01 = *(const s16x8*)(bptr + boff[ct0][1]);
            s16x8 b10 = *(const s16x8*)(bptr + boff[ct1][0]);
            s16x8 b11 = *(const s16x8*)(bptr + boff[ct1][1]);
            float m0 = -0.5f * cyS[it * TILE + pty[ct0]];
            float m1 = -0.5f * cyS[it * TILE + pty[ct1]];
            f32x4 s0 = {m0, m0, m0, m0};
            f32x4 s1 = {m1, m1, m1, m1};
            #pragma unroll
            for (int st = 0; st < 2; ++st) {
                f32x4 a0 = __builtin_amdgcn_mfma_f32_16x16x32_bf16(afrag[st][0], b00, s0, 0, 0, 0);
                a0 = __builtin_amdgcn_mfma_f32_16x16x32_bf16(afrag[st][1], b01, a0, 0, 0, 0);
                f32x4 a1 = __builtin_amdgcn_mfma_f32_16x16x32_bf16(afrag[st][0], b10, s1, 0, 0, 0);
                a1 = __builtin_amdgcn_mfma_f32_16x16x32_bf16(afrag[st][1], b11, a1, 0, 0, 0);
                #pragma unroll
                for (int r = 0; r < 4; ++r)
                    mx[st][r] = fmaxf(fmaxf(a0[r], a1[r]), mx[st][r]);   // v_max3
            }
        }
    }

    // butterfly max within 16 col-lanes, then share across wcol pair
    #pragma unroll
    for (int st = 0; st < 2; ++st)
        #pragma unroll
        for (int r = 0; r < 4; ++r)
            #pragma unroll
            for (int m = 1; m < 16; m <<= 1)
                mx[st][r] = fmaxf(mx[st][r], __shfl_xor(mx[st][r], m, 16));
    __syncthreads();
    if (c == 0) {
        #pragma unroll
        for (int st = 0; st < 2; ++st)
            #pragma unroll
            for (int r = 0; r < 4; ++r)
                xchg[w][st * 16 + 4 * h + r][0] = mx[st][r];
    }
    __syncthreads();
    #pragma unroll
    for (int st = 0; st < 2; ++st)
        #pragma unroll
        for (int r = 0; r < 4; ++r)
            mx[st][r] = fmaxf(mx[st][r], xchg[w ^ 1][st * 16 + 4 * h + r][0]);

    // gate thresholds + dthr reference (registers; ~60 VGPR total)
    float gthr[2][4], dthr[2][4], ssum[2][4], tsum[2][4];
    #pragma unroll
    for (int st = 0; st < 2; ++st)
        #pragma unroll
        for (int r = 0; r < 4; ++r) {
            float d2m = fmaf(-2.f, mx[st][r], x2v[st][r]);   // exact min d^2
            float mval = sqrtf(fmaxf(d2m, 0.f));
            dthr[st][r] = mval + MARGIN;
            gthr[st][r] = mx[st][r] - MARGIN * mval - HM2C;  // u>gthr <=> d<dthr
            ssum[st][r] = 0.f; tsum[st][r] = 0.f;
        }

    // re-prologue for pass 2
    #pragma unroll
    for (int q = 0; q < 4; ++q) {
        int e = q * 256 + tid;
        async16((char*)ys[0] + e * 16, cbase + e * 16);
    }

    // ================= PASS 2: gated weighted sums (ref = dthr) =============
    for (int it = 0; it < ITERS; ++it) {
        __syncthreads();                 // drains this tile's DMA
        if (it + 1 < ITERS) {
            const char* nsrc = cbase + (size_t)(it + 1) * TILE * ROWB;
            char* nbuf = (char*)ys[(it + 1) & 1];
            #pragma unroll
            for (int q = 0; q < 4; ++q) {
                int e = q * 256 + tid;
                async16(nbuf + e * 16, nsrc + e * 16);
            }
        }
        const char* bptr = (const char*)ys[it & 1];

        #pragma unroll
        for (int ct = 0; ct < 4; ++ct) {
            s16x8 b0 = *(const s16x8*)(bptr + boff[ct][0]);
            s16x8 b1 = *(const s16x8*)(bptr + boff[ct][1]);
            float m0 = -0.5f * cyS[it * TILE + pty[ct]];
            f32x4 seed = {m0, m0, m0, m0};
            #pragma unroll
            for (int st = 0; st < 2; ++st) {
                f32x4 a = __builtin_amdgcn_mfma_f32_16x16x32_bf16(afrag[st][0], b0, seed, 0, 0, 0);
                a = __builtin_amdgcn_mfma_f32_16x16x32_bf16(afrag[st][1], b1, a, 0, 0, 0);
                int hit = (a[0] > gthr[st][0]) | (a[1] > gthr[st][1]) |
                          (a[2] > gthr[st][2]) | (a[3] > gthr[st][3]);
                if (__any(hit)) {        // 16-row x 16-col group, ~30% fire
                    #pragma unroll
                    for (int r = 0; r < 4; ++r) {
                        float d2 = fmaf(-2.f, a[r], x2v[st][r]);
                        float d = sqrtf(fmaxf(d2, 0.f));
                        float e = __expf(INV_T * (dthr[st][r] - d));  // ->0 if far
                        ssum[st][r] += e;
                        tsum[st][r] = fmaf(e, d, tsum[st][r]);
                    }
                }
            }
        }
    }

    // butterfly sums within 16 col-lanes
    #pragma unroll
    for (int st = 0; st < 2; ++st)
        #pragma unroll
        for (int r = 0; r < 4; ++r)
            #pragma unroll
            for (int m = 1; m < 16; m <<= 1) {
                ssum[st][r] += __shfl_xor(ssum[st][r], m, 16);
                tsum[st][r] += __shfl_xor(tsum[st][r], m, 16);
            }

    // cross-wcol add and partial-state write {dthr, S, T}
    __syncthreads();
    if (c == 0) {
        #pragma unroll
        for (int st = 0; st < 2; ++st)
            #pragma unroll
            for (int r = 0; r < 4; ++r) {
                xchg[w][st * 16 + 4 * h + r][0] = ssum[st][r];
                xchg[w][st * 16 + 4 * h + r][1] = tsum[st][r];
            }
    }
    __syncthreads();
    if (wcol == 0 && c == 0) {
        int dirb = dir * 4 + b;
        #pragma unroll
        for (int st = 0; st < 2; ++st)
            #pragma unroll
            for (int r = 0; r < 4; ++r) {
                int row32 = st * 16 + 4 * h + r;
                float S = ssum[st][r] + xchg[w + 1][row32][0];
                float T = tsum[st][r] + xchg[w + 1][row32][1];
                int row = row0 + wrow * 32 + row32;
                float* pp = part + (((size_t)(dirb * MC + cs)) * NPTS + row) * 4;
                pp[0] = dthr[st][r]; pp[1] = S; pp[2] = T;
            }
    }
}

// Merge MC partial states per row (reference-consistent), cube, reduce.
__global__ __launch_bounds__(256) void merge_kernel(const float* __restrict__ part,
                                                    float* __restrict__ out) {
    __shared__ float red[4];
    int g = blockIdx.x * 256 + threadIdx.x;   // dirb*4096 + row
    int dirb = g >> 12;
    int row  = g & 4095;
    const float* p0 = part + (((size_t)dirb * MC) * NPTS + row) * 4;
    float mnv[MC], sv[MC], tv[MC];
    float nm = INFINITY;
    #pragma unroll
    for (int k = 0; k < MC; ++k) {
        const float* p = p0 + (size_t)k * NPTS * 4;
        mnv[k] = p[0]; sv[k] = p[1]; tv[k] = p[2];
        nm = fminf(nm, mnv[k]);
    }
    float S = 0.f, T = 0.f;
    #pragma unroll
    for (int k = 0; k < MC; ++k) {
        float cw = __expf(INV_T * (nm - mnv[k]));
        S += sv[k] * cw;
        T += tv[k] * cw;
    }
    float sm = T / S;
    float v = sm * sm * sm * SCALE;
    #pragma unroll
    for (int m = 1; m < 64; m <<= 1) v += __shfl_xor(v, m, 64);
    if ((threadIdx.x & 63) == 0) red[threadIdx.x >> 6] = v;
    __syncthreads();
    if (threadIdx.x == 0) atomicAdd(out, red[0] + red[1] + red[2] + red[3]);
}

extern "C" void kernel_launch(void* const* d_in, const int* in_sizes, int n_in,
                              void* d_out, int out_size, void* d_ws, size_t ws_size,
                              hipStream_t stream) {
    const float* x = (const float*)d_in[0];
    const float* y = (const float*)d_in[1];
    float* out = (float*)d_out;
    char* ws = (char*)d_ws;

    u16* xb = (u16*)(ws + OFF_XB);
    u16* yb = (u16*)(ws + OFF_YB);
    float* x2 = (float*)(ws + OFF_X2);
    float* y2 = (float*)(ws + OFF_Y2);
    float* part = (float*)(ws + OFF_PART);

    prep_kernel<<<dim3(1024, 2), 256, 0, stream>>>(x, y, xb, yb, x2, y2, out);
    softmin_fused<<<dim3(NPTS / 64, 4 * MC, 2), 256, 0, stream>>>(xb, yb, x2, y2, part);
    merge_kernel<<<128, 256, 0, stream>>>(part, out);
}

// Round 18
// 68.985 us; speedup vs baseline: 6.0429x; 1.2492x over previous
//
#include <hip/hip_runtime.h>
#include <math.h>

#define BATCH 4
#define NPTS 4096
#define DF 64
#define ROWB 128               // bytes per point row in bf16
#define TILE 128               // col tile per iter
#define MC 4                   // col chunks
#define CHUNK (NPTS / MC)      // 1024
#define ITERS (CHUNK / TILE)   // 8
#define INV_T 100.0f
#define MARGIN 0.16f           // skipped weights < exp(-16) ~ 1.1e-7
#define HM2C (0.5f * MARGIN * MARGIN)
#define SCALE (1.0f / 16384.0f)

typedef float  f32x4 __attribute__((ext_vector_type(4)));
typedef short  s16x8 __attribute__((ext_vector_type(8)));
typedef unsigned short u16;

// ws layout (6.19 MB, proven)
#define SZ_B   (BATCH * NPTS * DF * 2)   // bf16 array: 2 MB
#define SZ_N   (BATCH * NPTS * 4)        // norm array: 64 KB
#define OFF_XB 0
#define OFF_YB (OFF_XB + SZ_B)
#define OFF_X2 (OFF_YB + SZ_B)
#define OFF_Y2 (OFF_X2 + SZ_N)
#define OFF_PART (OFF_Y2 + SZ_N)         // [dirb][MC][NPTS][4] floats: 2 MB

__device__ __forceinline__ u16 f2bf(float f) {
    unsigned u = __float_as_uint(f);
    unsigned r = (u + 0x7fffu + ((u >> 16) & 1u)) >> 16;   // RNE
    return (u16)r;
}

// async 16B global -> LDS (DMA, no VGPR round-trip)
__device__ __forceinline__ void async16(void* lds, const void* g) {
    __builtin_amdgcn_global_load_lds(
        (const __attribute__((address_space(1))) unsigned int*)g,
        (__attribute__((address_space(3))) unsigned int*)lds, 16, 0, 0);
}

// fp32 -> bf16 (XOR-swizzled row layout: byte ^= (point&7)<<4) + fp32 norms.
__global__ __launch_bounds__(256) void prep_kernel(const float* __restrict__ X,
                                                   const float* __restrict__ Y,
                                                   u16* __restrict__ xb, u16* __restrict__ yb,
                                                   float* __restrict__ x2, float* __restrict__ y2,
                                                   float* __restrict__ out) {
    if (blockIdx.x == 0 && blockIdx.y == 0 && threadIdx.x == 0) out[0] = 0.0f;
    const float* src = blockIdx.y ? Y : X;
    u16* dstb   = blockIdx.y ? yb : xb;
    float* dstn = blockIdx.y ? y2 : x2;
    int g = blockIdx.x * 256 + threadIdx.x;
    int p = g >> 4;                       // point 0..16383
    int sub = g & 15;                     // 8B chunk within row
    float4 v = ((const float4*)src)[(size_t)p * 16 + sub];
    float n4 = v.x * v.x + v.y * v.y + v.z * v.z + v.w * v.w;
    #pragma unroll
    for (int m = 1; m < 16; m <<= 1) n4 += __shfl_xor(n4, m, 16);
    ushort4 hh;
    hh.x = f2bf(v.x); hh.y = f2bf(v.y); hh.z = f2bf(v.z); hh.w = f2bf(v.w);
    int byteoff = (sub << 3) ^ ((p & 7) << 4);   // swizzle (XOR bits 4..6)
    *(ushort4*)((char*)dstb + (size_t)p * ROWB + byteoff) = hh;
    if (sub == 0) dstn[p] = n4;
}

// Two-phase partial softmin (R14 skeleton + dthr-precompute only).
// Block = 64 rows x 1024 cols, wave tiling 2x2 (wave: 32 rows x 64 cols/tile).
// MFMA C seeded with -y2/2 so u = a[r]. Pass 1: 1 fmax/elem. Pass 2: per-r
// 4x16-slice gate (~9% fire), dthr reference precomputed in registers.
__global__ __launch_bounds__(256, 4) void softmin_fused(const u16* __restrict__ xb,
                                                        const u16* __restrict__ yb,
                                                        const float* __restrict__ x2g,
                                                        const float* __restrict__ y2g,
                                                        float* __restrict__ part) {
    __shared__ u16 ys[2][TILE * DF];     // 2 x 16 KB double buffer
    __shared__ float cyS[CHUNK];         // 4 KB col norms
    __shared__ float xchg[4][32][2];

    const int tid = threadIdx.x;
    const int nt  = blockIdx.x;
    const int b   = blockIdx.y & 3;
    const int cs  = blockIdx.y >> 2;
    const int dir = blockIdx.z;

    const u16 *rowsrc, *colsrc; const float *rn, *cn;
    if (dir == 0) { rowsrc = xb; colsrc = yb; rn = x2g; cn = y2g; }
    else          { rowsrc = yb; colsrc = xb; rn = y2g; cn = x2g; }

    const int w    = tid >> 6;
    const int wrow = w >> 1, wcol = w & 1;
    const int h    = (tid >> 4) & 3;     // k-octet / D-row group
    const int c    = tid & 15;           // fragment lane slot

    const size_t bpts = (size_t)b * NPTS;
    const int row0 = nt * 64;
    const char* rbase = (const char*)(rowsrc + (bpts + row0) * DF);
    const char* cbase = (const char*)(colsrc + (bpts + (size_t)cs * CHUNK) * DF);
    const float* cnb = cn + bpts + (size_t)cs * CHUNK;

    // loop-invariant B fragment offsets + col point ids (4 x 16-col groups)
    int boff[4][2], pty[4];
    #pragma unroll
    for (int ct = 0; ct < 4; ++ct) {
        int p = wcol * 64 + ct * 16 + c;
        pty[ct] = p;
        #pragma unroll
        for (int kp = 0; kp < 2; ++kp)
            boff[ct][kp] = p * ROWB + ((h * 16 + kp * 64) ^ ((p & 7) << 4));
    }

    // ---- prologue: DMA first y tile; stage col norms; A-frags from global ----
    #pragma unroll
    for (int q = 0; q < 4; ++q) {
        int e = q * 256 + tid;
        async16((char*)ys[0] + e * 16, cbase + e * 16);
    }
    *(float4*)&cyS[tid * 4] = ((const float4*)cnb)[tid];   // 1024 col norms

    s16x8 afrag[2][2];
    #pragma unroll
    for (int st = 0; st < 2; ++st) {
        int rr = (wrow * 2 + st) * 16 + c;
        #pragma unroll
        for (int kp = 0; kp < 2; ++kp) {
            int o = (h * 16 + kp * 64) ^ ((rr & 7) << 4);
            afrag[st][kp] = *(const s16x8*)(rbase + rr * ROWB + o);
        }
    }
    float x2v[2][4];
    #pragma unroll
    for (int st = 0; st < 2; ++st)
        #pragma unroll
        for (int r = 0; r < 4; ++r)
            x2v[st][r] = rn[bpts + row0 + (wrow * 2 + st) * 16 + 4 * h + r];

    float mx[2][4];
    #pragma unroll
    for (int st = 0; st < 2; ++st)
        #pragma unroll
        for (int r = 0; r < 4; ++r) mx[st][r] = -INFINITY;

    __syncthreads();   // drains DMA + cyS writes

    // ================= PASS 1: chunk max of u = x.y - y2/2 (C-seeded) =======
    for (int it = 0; it < ITERS; ++it) {
        if (it > 0) __syncthreads();     // tile(it) DMA drained
        if (it + 1 < ITERS) {            // issue next tile (overlaps compute)
            const char* nsrc = cbase + (size_t)(it + 1) * TILE * ROWB;
            char* nbuf = (char*)ys[(it + 1) & 1];
            #pragma unroll
            for (int q = 0; q < 4; ++q) {
                int e = q * 256 + tid;
                async16(nbuf + e * 16, nsrc + e * 16);
            }
        }
        const char* bptr = (const char*)ys[it & 1];

        #pragma unroll
        for (int ct = 0; ct < 4; ++ct) {
            s16x8 b0 = *(const s16x8*)(bptr + boff[ct][0]);
            s16x8 b1 = *(const s16x8*)(bptr + boff[ct][1]);
            float m0 = -0.5f * cyS[it * TILE + pty[ct]];
            f32x4 seed = {m0, m0, m0, m0};
            #pragma unroll
            for (int st = 0; st < 2; ++st) {
                f32x4 a = __builtin_amdgcn_mfma_f32_16x16x32_bf16(afrag[st][0], b0, seed, 0, 0, 0);
                a = __builtin_amdgcn_mfma_f32_16x16x32_bf16(afrag[st][1], b1, a, 0, 0, 0);
                #pragma unroll
                for (int r = 0; r < 4; ++r)
                    mx[st][r] = fmaxf(mx[st][r], a[r]);   // u = a[r] directly
            }
        }
    }

    // butterfly max within 16 col-lanes, then share across wcol pair
    #pragma unroll
    for (int st = 0; st < 2; ++st)
        #pragma unroll
        for (int r = 0; r < 4; ++r)
            #pragma unroll
            for (int m = 1; m < 16; m <<= 1)
                mx[st][r] = fmaxf(mx[st][r], __shfl_xor(mx[st][r], m, 16));
    __syncthreads();
    if (c == 0) {
        #pragma unroll
        for (int st = 0; st < 2; ++st)
            #pragma unroll
            for (int r = 0; r < 4; ++r)
                xchg[w][st * 16 + 4 * h + r][0] = mx[st][r];
    }
    __syncthreads();
    #pragma unroll
    for (int st = 0; st < 2; ++st)
        #pragma unroll
        for (int r = 0; r < 4; ++r)
            mx[st][r] = fmaxf(mx[st][r], xchg[w ^ 1][st * 16 + 4 * h + r][0]);

    // gate thresholds + dthr reference precomputed in registers (~60 VGPR)
    float gthr[2][4], dthr[2][4], ssum[2][4], tsum[2][4];
    #pragma unroll
    for (int st = 0; st < 2; ++st)
        #pragma unroll
        for (int r = 0; r < 4; ++r) {
            float d2m = fmaf(-2.f, mx[st][r], x2v[st][r]);   // exact min d^2
            float mval = sqrtf(fmaxf(d2m, 0.f));
            dthr[st][r] = mval + MARGIN;
            gthr[st][r] = mx[st][r] - MARGIN * mval - HM2C;  // u>gthr <=> d<dthr
            ssum[st][r] = 0.f; tsum[st][r] = 0.f;
        }

    // re-prologue for pass 2
    #pragma unroll
    for (int q = 0; q < 4; ++q) {
        int e = q * 256 + tid;
        async16((char*)ys[0] + e * 16, cbase + e * 16);
    }

    // ================= PASS 2: gated weighted sums (ref = dthr) =============
    for (int it = 0; it < ITERS; ++it) {
        __syncthreads();                 // drains this tile's DMA
        if (it + 1 < ITERS) {
            const char* nsrc = cbase + (size_t)(it + 1) * TILE * ROWB;
            char* nbuf = (char*)ys[(it + 1) & 1];
            #pragma unroll
            for (int q = 0; q < 4; ++q) {
                int e = q * 256 + tid;
                async16(nbuf + e * 16, nsrc + e * 16);
            }
        }
        const char* bptr = (const char*)ys[it & 1];

        #pragma unroll
        for (int ct = 0; ct < 4; ++ct) {
            s16x8 b0 = *(const s16x8*)(bptr + boff[ct][0]);
            s16x8 b1 = *(const s16x8*)(bptr + boff[ct][1]);
            float m0 = -0.5f * cyS[it * TILE + pty[ct]];
            f32x4 seed = {m0, m0, m0, m0};
            #pragma unroll
            for (int st = 0; st < 2; ++st) {
                f32x4 a = __builtin_amdgcn_mfma_f32_16x16x32_bf16(afrag[st][0], b0, seed, 0, 0, 0);
                a = __builtin_amdgcn_mfma_f32_16x16x32_bf16(afrag[st][1], b1, a, 0, 0, 0);
                #pragma unroll
                for (int r = 0; r < 4; ++r) {
                    if (__any(a[r] > gthr[st][r])) {   // 4-row x 16-col slice, ~9%
                        float d2 = fmaf(-2.f, a[r], x2v[st][r]);
                        float d = sqrtf(fmaxf(d2, 0.f));
                        float e = __expf(INV_T * (dthr[st][r] - d));  // ->0 if far
                        ssum[st][r] += e;
                        tsum[st][r] = fmaf(e, d, tsum[st][r]);
                    }
                }
            }
        }
    }

    // butterfly sums within 16 col-lanes
    #pragma unroll
    for (int st = 0; st < 2; ++st)
        #pragma unroll
        for (int r = 0; r < 4; ++r)
            #pragma unroll
            for (int m = 1; m < 16; m <<= 1) {
                ssum[st][r] += __shfl_xor(ssum[st][r], m, 16);
                tsum[st][r] += __shfl_xor(tsum[st][r], m, 16);
            }

    // cross-wcol add and partial-state write {dthr, S, T}
    __syncthreads();
    if (c == 0) {
        #pragma unroll
        for (int st = 0; st < 2; ++st)
            #pragma unroll
            for (int r = 0; r < 4; ++r) {
                xchg[w][st * 16 + 4 * h + r][0] = ssum[st][r];
                xchg[w][st * 16 + 4 * h + r][1] = tsum[st][r];
            }
    }
    __syncthreads();
    if (wcol == 0 && c == 0) {
        int dirb = dir * 4 + b;
        #pragma unroll
        for (int st = 0; st < 2; ++st)
            #pragma unroll
            for (int r = 0; r < 4; ++r) {
                int row32 = st * 16 + 4 * h + r;
                float S = ssum[st][r] + xchg[w + 1][row32][0];
                float T = tsum[st][r] + xchg[w + 1][row32][1];
                int row = row0 + wrow * 32 + row32;
                float* pp = part + (((size_t)(dirb * MC + cs)) * NPTS + row) * 4;
                pp[0] = dthr[st][r]; pp[1] = S; pp[2] = T;
            }
    }
}

// Merge MC partial states per row (reference-consistent), cube, reduce.
__global__ __launch_bounds__(256) void merge_kernel(const float* __restrict__ part,
                                                    float* __restrict__ out) {
    __shared__ float red[4];
    int g = blockIdx.x * 256 + threadIdx.x;   // dirb*4096 + row
    int dirb = g >> 12;
    int row  = g & 4095;
    const float* p0 = part + (((size_t)dirb * MC) * NPTS + row) * 4;
    float mnv[MC], sv[MC], tv[MC];
    float nm = INFINITY;
    #pragma unroll
    for (int k = 0; k < MC; ++k) {
        const float* p = p0 + (size_t)k * NPTS * 4;
        mnv[k] = p[0]; sv[k] = p[1]; tv[k] = p[2];
        nm = fminf(nm, mnv[k]);
    }
    float S = 0.f, T = 0.f;
    #pragma unroll
    for (int k = 0; k < MC; ++k) {
        float cw = __expf(INV_T * (nm - mnv[k]));
        S += sv[k] * cw;
        T += tv[k] * cw;
    }
    float sm = T / S;
    float v = sm * sm * sm * SCALE;
    #pragma unroll
    for (int m = 1; m < 64; m <<= 1) v += __shfl_xor(v, m, 64);
    if ((threadIdx.x & 63) == 0) red[threadIdx.x >> 6] = v;
    __syncthreads();
    if (threadIdx.x == 0) atomicAdd(out, red[0] + red[1] + red[2] + red[3]);
}

extern "C" void kernel_launch(void* const* d_in, const int* in_sizes, int n_in,
                              void* d_out, int out_size, void* d_ws, size_t ws_size,
                              hipStream_t stream) {
    const float* x = (const float*)d_in[0];
    const float* y = (const float*)d_in[1];
    float* out = (float*)d_out;
    char* ws = (char*)d_ws;

    u16* xb = (u16*)(ws + OFF_XB);
    u16* yb = (u16*)(ws + OFF_YB);
    float* x2 = (float*)(ws + OFF_X2);
    float* y2 = (float*)(ws + OFF_Y2);
    float* part = (float*)(ws + OFF_PART);

    prep_kernel<<<dim3(1024, 2), 256, 0, stream>>>(x, y, xb, yb, x2, y2, out);
    softmin_fused<<<dim3(NPTS / 64, 4 * MC, 2), 256, 0, stream>>>(xb, yb, x2, y2, part);
    merge_kernel<<<128, 256, 0, stream>>>(part, out);
}